// Round 2
// baseline (1051.812 us; speedup 1.0000x reference)
//
#include <hip/hip_runtime.h>
#include <cstdio>

#define B_   64
#define S_   512
#define D_   512
#define H_   8
#define DK_  64
#define DFF_ 1024
#define L_   2

typedef __attribute__((ext_vector_type(8))) short bf16x8;
typedef __attribute__((ext_vector_type(4))) float f32x4;

__device__ inline short f2bf(float f) {
  unsigned u = __float_as_uint(f);
  u = u + 0x7FFF + ((u >> 16) & 1);
  return (short)(u >> 16);
}
__device__ inline float bf2f(short s) {
  return __uint_as_float(((unsigned)(unsigned short)s) << 16);
}

// ---------------- positional encoding table ----------------
__global__ void pe_kernel(float* __restrict__ pe) {
  int idx = blockIdx.x * 256 + threadIdx.x;      // S_*D_ threads
  int s = idx >> 9, d = idx & 511;
  float dv = __expf((float)(d & ~1) * (-9.210340371976184f / (float)D_));
  float ang = (float)s * dv;
  pe[idx] = (d & 1) ? cosf(ang) : sinf(ang);
}

// x = q + pe (f32 master + bf16 mirror); yb = bf16(qa + pe)
__global__ void prep_kernel(const float* __restrict__ q, const float* __restrict__ qa,
                            const float* __restrict__ pe, float* __restrict__ x,
                            short* __restrict__ xb, short* __restrict__ yb) {
  size_t idx = (size_t)blockIdx.x * 256 + threadIdx.x;
  int sd = (int)(idx & (size_t)(S_ * D_ - 1));
  float p = pe[sd];
  float xv = q[idx] + p;
  x[idx] = xv;
  xb[idx] = f2bf(xv);
  yb[idx] = f2bf(qa[idx] + p);
}

// dst[c][r] = bf16(src[r][c]); src is R x C row-major
__global__ void tr_bf16(const float* __restrict__ src, short* __restrict__ dst, int R, int C) {
  int idx = blockIdx.x * 256 + threadIdx.x;
  if (idx >= R * C) return;
  int r = idx / C, c = idx - r * C;
  dst[(size_t)c * R + r] = f2bf(src[idx]);
}

// ---------------- bf16 MFMA GEMM: C[M,N] = A[M,K] @ BT[N,K]^T + bias ----------------
// 128x128 tile, BK=32, 256 threads (4 waves, 2x2), acc 4x4 16x16 fragments per wave.
__global__ __launch_bounds__(256) void gemm_bt(
    const short* __restrict__ A, const short* __restrict__ BT,
    const float* __restrict__ bias, short* __restrict__ Cb,
    int M, int N, int K, int relu)
{
  __shared__ short As[128][40];
  __shared__ short Bs[128][40];
  const int t = threadIdx.x;
  const int bcol = blockIdx.x, brow = blockIdx.y;
  const int w = t >> 6, lane = t & 63, lr = lane & 15, lk = lane >> 4;
  const int wrow = w >> 1, wcol = w & 1;

  const f32x4 vzero = {0.f, 0.f, 0.f, 0.f};
  f32x4 acc[4][4];
#pragma unroll
  for (int m = 0; m < 4; ++m)
#pragma unroll
    for (int n = 0; n < 4; ++n) acc[m][n] = vzero;

  const short* Abase = A + (size_t)brow * 128 * K;
  const short* Bbase = BT + (size_t)bcol * 128 * K;

  for (int k0 = 0; k0 < K; k0 += 32) {
    __syncthreads();
#pragma unroll
    for (int it = 0; it < 2; ++it) {
      int c = t + it * 256;          // 512 chunks of 8 shorts
      int row = c >> 2, seg = c & 3;
      *(f32x4*)&As[row][seg * 8] = *(const f32x4*)(Abase + (size_t)row * K + k0 + seg * 8);
      *(f32x4*)&Bs[row][seg * 8] = *(const f32x4*)(Bbase + (size_t)row * K + k0 + seg * 8);
    }
    __syncthreads();

    bf16x8 af[4], bf[4];
#pragma unroll
    for (int m = 0; m < 4; ++m) af[m] = *(const bf16x8*)&As[wrow * 64 + m * 16 + lr][lk * 8];
#pragma unroll
    for (int n = 0; n < 4; ++n) bf[n] = *(const bf16x8*)&Bs[wcol * 64 + n * 16 + lr][lk * 8];
#pragma unroll
    for (int m = 0; m < 4; ++m)
#pragma unroll
      for (int n = 0; n < 4; ++n)
        acc[m][n] = __builtin_amdgcn_mfma_f32_16x16x32_bf16(af[m], bf[n], acc[m][n], 0, 0, 0);
  }

#pragma unroll
  for (int m = 0; m < 4; ++m)
#pragma unroll
    for (int n = 0; n < 4; ++n) {
      int col = bcol * 128 + wcol * 64 + n * 16 + lr;
      float bvv = bias ? bias[col] : 0.f;
#pragma unroll
      for (int j = 0; j < 4; ++j) {
        int row = brow * 128 + wrow * 64 + m * 16 + lk * 4 + j;
        float vv = acc[m][n][j] + bvv;
        if (relu) vv = fmaxf(vv, 0.f);
        Cb[(size_t)row * N + col] = f2bf(vv);
      }
    }
}

// ---------------- fused attention ----------------
// grid (S/32, H, B), 256 threads (4 waves). Per block: 32 q-rows of one head.
// scores = (qk @ qk^T) * scale * fr[q]; strict-lower mask; softmax; P @ v.
__global__ __launch_bounds__(256) void attn_kernel(
    const short* __restrict__ qk, const short* __restrict__ v,
    const float* __restrict__ fr, short* __restrict__ out)
{
  const int qb = blockIdx.x, h = blockIdx.y, b = blockIdx.z;
  const int t = threadIdx.x;
  const int w = t >> 6, lane = t & 63, lr = lane & 15, lk = lane >> 4;

  __shared__ short P[32][520];
  __shared__ float redmax[32][4];
  __shared__ float redsum[32][4];

  const size_t bh = (size_t)b * S_ * D_ + (size_t)h * DK_;
  const float NEGBIG = -3.0e38f;

  // Q fragments (A operand): rows qb*32 + qt*16 + lr, dk slice ks*32 + lk*8
  bf16x8 qf[2][2];
#pragma unroll
  for (int qt = 0; qt < 2; ++qt)
#pragma unroll
    for (int ks = 0; ks < 2; ++ks)
      qf[qt][ks] = *(const bf16x8*)(qk + bh + (size_t)(qb * 32 + qt * 16 + lr) * D_ + ks * 32 + lk * 8);

  const f32x4 vzero = {0.f, 0.f, 0.f, 0.f};
  f32x4 acc[2][8];
#pragma unroll
  for (int qt = 0; qt < 2; ++qt)
#pragma unroll
    for (int kt = 0; kt < 8; ++kt) acc[qt][kt] = vzero;

  // scores: this wave owns key columns [w*128, w*128+128)
#pragma unroll
  for (int kt = 0; kt < 8; ++kt) {
    const int kbase = w * 128 + kt * 16;
#pragma unroll
    for (int ks = 0; ks < 2; ++ks) {
      bf16x8 kf = *(const bf16x8*)(qk + bh + (size_t)(kbase + lr) * D_ + ks * 32 + lk * 8);
      acc[0][kt] = __builtin_amdgcn_mfma_f32_16x16x32_bf16(qf[0][ks], kf, acc[0][kt], 0, 0, 0);
      acc[1][kt] = __builtin_amdgcn_mfma_f32_16x16x32_bf16(qf[1][ks], kf, acc[1][kt], 0, 0, 0);
    }
  }

  const float scale = 0.125f;   // 1/sqrt(64)
  float frv[2][4], rmax[2][4], rsum[2][4];
#pragma unroll
  for (int qt = 0; qt < 2; ++qt)
#pragma unroll
    for (int j = 0; j < 4; ++j) {
      int qrow = qb * 32 + qt * 16 + lk * 4 + j;
      frv[qt][j] = scale * fr[(size_t)b * S_ + qrow];
      rmax[qt][j] = NEGBIG;
      rsum[qt][j] = 0.f;
    }

  // pass 1: masked row max
#pragma unroll
  for (int qt = 0; qt < 2; ++qt)
#pragma unroll
    for (int kt = 0; kt < 8; ++kt)
#pragma unroll
      for (int j = 0; j < 4; ++j) {
        int qrow = qb * 32 + qt * 16 + lk * 4 + j;
        int kcol = w * 128 + kt * 16 + lr;
        if (kcol < qrow) rmax[qt][j] = fmaxf(rmax[qt][j], acc[qt][kt][j] * frv[qt][j]);
      }
#pragma unroll
  for (int m = 1; m < 16; m <<= 1)
#pragma unroll
    for (int qt = 0; qt < 2; ++qt)
#pragma unroll
      for (int j = 0; j < 4; ++j)
        rmax[qt][j] = fmaxf(rmax[qt][j], __shfl_xor(rmax[qt][j], m));
  if (lr == 0) {
#pragma unroll
    for (int qt = 0; qt < 2; ++qt)
#pragma unroll
      for (int j = 0; j < 4; ++j) redmax[qt * 16 + lk * 4 + j][w] = rmax[qt][j];
  }
  __syncthreads();
#pragma unroll
  for (int qt = 0; qt < 2; ++qt)
#pragma unroll
    for (int j = 0; j < 4; ++j) {
      int row = qt * 16 + lk * 4 + j;
      rmax[qt][j] = fmaxf(fmaxf(redmax[row][0], redmax[row][1]),
                          fmaxf(redmax[row][2], redmax[row][3]));
    }

  // pass 2: exp (unnormalized), row sums, write P (bf16) to LDS
#pragma unroll
  for (int qt = 0; qt < 2; ++qt)
#pragma unroll
    for (int kt = 0; kt < 8; ++kt)
#pragma unroll
      for (int j = 0; j < 4; ++j) {
        int qrow = qb * 32 + qt * 16 + lk * 4 + j;
        int kcol = w * 128 + kt * 16 + lr;
        float e = 0.f;
        if (kcol < qrow) e = __expf(acc[qt][kt][j] * frv[qt][j] - rmax[qt][j]);
        rsum[qt][j] += e;
        P[qt * 16 + lk * 4 + j][w * 128 + kt * 16 + lr] = f2bf(e);
      }
#pragma unroll
  for (int m = 1; m < 16; m <<= 1)
#pragma unroll
    for (int qt = 0; qt < 2; ++qt)
#pragma unroll
      for (int j = 0; j < 4; ++j) rsum[qt][j] += __shfl_xor(rsum[qt][j], m);
  if (lr == 0) {
#pragma unroll
    for (int qt = 0; qt < 2; ++qt)
#pragma unroll
      for (int j = 0; j < 4; ++j) redsum[qt * 16 + lk * 4 + j][w] = rsum[qt][j];
  }
  __syncthreads();   // P fully written + redsum ready

  // PV: wave w -> q-half (w>>1), dk-half (w&1); output [16 q x 32 dk]
  const int qhalf = w >> 1, dhalf = w & 1;
  float invd[4];
#pragma unroll
  for (int j = 0; j < 4; ++j) {
    int row = qhalf * 16 + lk * 4 + j;
    float dsum = redsum[row][0] + redsum[row][1] + redsum[row][2] + redsum[row][3];
    invd[j] = dsum > 0.f ? 1.f / dsum : 0.f;   // row 0 -> 0 (zero_pad)
  }

  f32x4 oacc[2] = {vzero, vzero};
  for (int kb = 0; kb < 16; ++kb) {
    bf16x8 pf = *(const bf16x8*)&P[qhalf * 16 + lr][kb * 32 + lk * 8];
#pragma unroll
    for (int n = 0; n < 2; ++n) {
      bf16x8 vf;
#pragma unroll
      for (int j = 0; j < 8; ++j)
        vf[j] = v[bh + (size_t)(kb * 32 + lk * 8 + j) * D_ + dhalf * 32 + n * 16 + lr];
      oacc[n] = __builtin_amdgcn_mfma_f32_16x16x32_bf16(pf, vf, oacc[n], 0, 0, 0);
    }
  }

#pragma unroll
  for (int n = 0; n < 2; ++n)
#pragma unroll
    for (int j = 0; j < 4; ++j) {
      int qrow = qb * 32 + qhalf * 16 + lk * 4 + j;
      out[bh + (size_t)qrow * D_ + dhalf * 32 + n * 16 + lr] = f2bf(oacc[n][j] * invd[j]);
    }
}

// ---------------- fused residual + LayerNorm ----------------
// one wave per row; x_out = LN(x_in + add) with gamma/beta; also bf16 mirror.
__global__ __launch_bounds__(256) void ln_res(
    const float* __restrict__ xin, const short* __restrict__ add,
    const float* __restrict__ g, const float* __restrict__ bb,
    float* __restrict__ xout, short* __restrict__ xbout)
{
  const int row = blockIdx.x * 4 + (threadIdx.x >> 6);
  const int lane = threadIdx.x & 63;
  const size_t base = (size_t)row * D_ + lane * 8;

  f32x4 a0 = *(const f32x4*)(xin + base);
  f32x4 a1 = *(const f32x4*)(xin + base + 4);
  bf16x8 av = *(const bf16x8*)(add + base);
  float vals[8];
#pragma unroll
  for (int i = 0; i < 4; ++i) vals[i] = a0[i] + bf2f(av[i]);
#pragma unroll
  for (int i = 0; i < 4; ++i) vals[4 + i] = a1[i] + bf2f(av[4 + i]);

  float s = 0.f, sq = 0.f;
#pragma unroll
  for (int i = 0; i < 8; ++i) { s += vals[i]; sq += vals[i] * vals[i]; }
#pragma unroll
  for (int m = 1; m < 64; m <<= 1) { s += __shfl_xor(s, m); sq += __shfl_xor(sq, m); }

  float mean = s * (1.f / D_);
  float var = sq * (1.f / D_) - mean * mean;
  float rstd = rsqrtf(var + 1e-5f);

  int col = lane * 8;
  f32x4 o0, o1; bf16x8 ob;
#pragma unroll
  for (int i = 0; i < 8; ++i) {
    float vv = g[col + i] * (vals[i] - mean) * rstd + bb[col + i];
    if (i < 4) o0[i] = vv; else o1[i - 4] = vv;
    ob[i] = f2bf(vv);
  }
  *(f32x4*)(xout + base) = o0;
  *(f32x4*)(xout + base + 4) = o1;
  *(bf16x8*)(xbout + base) = ob;
}

// ---------------- host ----------------
extern "C" void kernel_launch(void* const* d_in, const int* in_sizes, int n_in,
                              void* d_out, int out_size, void* d_ws, size_t ws_size,
                              hipStream_t stream) {
  const float* q_emb = (const float*)d_in[0];
  const float* qa_emb = (const float*)d_in[1];
  const float* frate = (const float*)d_in[2];
  const float* Wk = (const float*)d_in[3];
  const float* bk = (const float*)d_in[4];
  const float* Wv = (const float*)d_in[5];
  const float* bv = (const float*)d_in[6];
  const float* Wo = (const float*)d_in[7];
  const float* bo = (const float*)d_in[8];
  const float* ln1g = (const float*)d_in[9];
  const float* ln1b = (const float*)d_in[10];
  const float* W1 = (const float*)d_in[11];
  const float* b1 = (const float*)d_in[12];
  const float* W2 = (const float*)d_in[13];
  const float* b2 = (const float*)d_in[14];
  const float* ln2g = (const float*)d_in[15];
  const float* ln2b = (const float*)d_in[16];
  float* x = (float*)d_out;

  char* ws = (char*)d_ws;
  size_t off = 0;
  auto alloc = [&](size_t bytes) -> void* {
    void* p = ws + off;
    off += (bytes + 255) & ~(size_t)255;
    return p;
  };
  const size_t MTOK = (size_t)B_ * S_;   // 32768 rows
  float* pe    = (float*)alloc((size_t)S_ * D_ * 4);
  short* xb    = (short*)alloc(MTOK * D_ * 2);
  short* yb    = (short*)alloc(MTOK * D_ * 2);
  short* qkb   = (short*)alloc(MTOK * D_ * 2);
  short* vb    = (short*)alloc(MTOK * D_ * 2);
  short* ff1b  = (short*)alloc(MTOK * DFF_ * 2);
  // lifetime-based aliases (saves 64 MB; fits 256 MiB workspace):
  //   attnb (attn->WoGEMM) aliases ff1b (ff1GEMM->ff2GEMM) -- disjoint within a layer
  //   goutb (WoGEMM/ff2GEMM -> ln_res) aliases qkb (dead after attn_kernel)
  short* attnb = ff1b;
  short* goutb = qkb;
  short* wT[L_][5];
  for (int i = 0; i < L_; ++i) {
    wT[i][0] = (short*)alloc((size_t)D_ * D_ * 2);     // WkT [D][D]
    wT[i][1] = (short*)alloc((size_t)D_ * D_ * 2);     // WvT
    wT[i][2] = (short*)alloc((size_t)D_ * D_ * 2);     // WoT
    wT[i][3] = (short*)alloc((size_t)D_ * DFF_ * 2);   // W1T [DFF][D]
    wT[i][4] = (short*)alloc((size_t)DFF_ * D_ * 2);   // W2T [D][DFF]
  }
  if (off > ws_size) {
    fprintf(stderr, "parKT: workspace overflow: need %zu have %zu\n", off, ws_size);
    return;
  }

  pe_kernel<<<(S_ * D_) / 256, 256, 0, stream>>>(pe);
  prep_kernel<<<(int)(MTOK * D_ / 256), 256, 0, stream>>>(q_emb, qa_emb, pe, x, xb, yb);

  for (int i = 0; i < L_; ++i) {
    tr_bf16<<<(D_ * D_ + 255) / 256, 256, 0, stream>>>(Wk + (size_t)i * D_ * D_, wT[i][0], D_, D_);
    tr_bf16<<<(D_ * D_ + 255) / 256, 256, 0, stream>>>(Wv + (size_t)i * D_ * D_, wT[i][1], D_, D_);
    tr_bf16<<<(D_ * D_ + 255) / 256, 256, 0, stream>>>(Wo + (size_t)i * D_ * D_, wT[i][2], D_, D_);
    tr_bf16<<<(D_ * DFF_ + 255) / 256, 256, 0, stream>>>(W1 + (size_t)i * D_ * DFF_, wT[i][3], D_, DFF_);
    tr_bf16<<<(DFF_ * D_ + 255) / 256, 256, 0, stream>>>(W2 + (size_t)i * DFF_ * D_, wT[i][4], DFF_, D_);
  }

  const int M = (int)MTOK;
  for (int i = 0; i < L_; ++i) {
    gemm_bt<<<dim3(D_ / 128, M / 128), 256, 0, stream>>>(xb, wT[i][0], bk + (size_t)i * D_, qkb, M, D_, D_, 0);
    gemm_bt<<<dim3(D_ / 128, M / 128), 256, 0, stream>>>(yb, wT[i][1], bv + (size_t)i * D_, vb, M, D_, D_, 0);
    attn_kernel<<<dim3(S_ / 32, H_, B_), 256, 0, stream>>>(qkb, vb, frate, attnb);
    gemm_bt<<<dim3(D_ / 128, M / 128), 256, 0, stream>>>(attnb, wT[i][2], bo + (size_t)i * D_, goutb, M, D_, D_, 0);
    ln_res<<<M / 4, 256, 0, stream>>>(x, goutb, ln1g + (size_t)i * D_, ln1b + (size_t)i * D_, x, xb);
    gemm_bt<<<dim3(DFF_ / 128, M / 128), 256, 0, stream>>>(xb, wT[i][3], b1 + (size_t)i * DFF_, ff1b, M, DFF_, D_, 1);
    gemm_bt<<<dim3(D_ / 128, M / 128), 256, 0, stream>>>(ff1b, wT[i][4], b2 + (size_t)i * D_, goutb, M, D_, DFF_, 0);
    ln_res<<<M / 4, 256, 0, stream>>>(x, goutb, ln2g + (size_t)i * D_, ln2b + (size_t)i * D_, x, xb);
  }
}